// Round 12
// baseline (604.492 us; speedup 1.0000x reference)
//
#include <hip/hip_runtime.h>

// R19: A/B ROUND — probe = V5 "token-per-lane" body x REP=8, final = R14.
// R18 post-mortem: occupancy 64% yet slower -> occupancy never binding;
// VALU 33%, HBM 4%, no conflicts -> shared-pipe issue cost. Audit points at
// the token loop's ~320 uniform-broadcast ds_read_b128/row (all 64 lanes
// read the same 16B; channel-per-lane needs every token broadcast): 16
// rows/CU x 320 x ~6-12cy ~= 10-16us of per-CU LDS pipe = the unexplained
// bulk of R16's 24us warm body. V5: each lane owns 4 tokens via DISTINCT
// ds_reads (5 b128/wave total), computes all 32 channels into v[64] regs
// (weights via wave-uniform s_load on the SMEM pipe), NaN-safe cndmask
// masks, then a 63-step shfl butterfly -> exactly R14's sAcc layout.
// Token work becomes L-independent -> straggler drain also fixed.
// Decode: dur(probe)=f+8*b5 from top-5 (with counters); score ~= 111 +
// dur(probe) + 30. b5<=12 -> ship V5 solo next round.

#define BDIM 64

__device__ __forceinline__ void gld16(const void* g, void* l) {
    __builtin_amdgcn_global_load_lds((__attribute__((address_space(1))) void*)g,
                                     (__attribute__((address_space(3))) void*)l,
                                     16, 0, 0);
}

// ---------------- shared cat+tail (identical in both bodies) ----------------
__device__ __forceinline__ void cat_tail(
    const int* __restrict__ cat_c,
    const float* __restrict__ w_p2, const float* __restrict__ b_p2,
    const float* __restrict__ w_c2, const float* __restrict__ b_c2,
    const float* __restrict__ emb_g,  const float* __restrict__ emb_k,
    const float* __restrict__ emb_pr, const float* __restrict__ emb_j,
    const float* __restrict__ emb_r,  const float* __restrict__ emb_pl,
    const float* __restrict__ emb_a,
    const float* __restrict__ w_fc1, const float* __restrict__ b_fc1,
    const float* __restrict__ w_fc2, const float* __restrict__ b_fc2,
    float* __restrict__ out,
    float* sBuf, int lane, int b, int L, float Lf, float invL,
    int4 qc0, int4 qc1, bool hc0, bool hc1)
{
    int*   sKp  = (int*)(sBuf + 1280);
    int*   hist = (int*)sBuf;
    float* sAcc = sBuf + 768;
    float* sPool = sBuf + 832;
    const int ch = lane & 31, h = lane >> 5;
    const int limc = 2 * L;

    hist[lane] = 0;
    if (lane < 32) hist[64 + lane] = 0;

    int sg = 0, sk = 0, sp = 0;
    {
        const int limp = 5 * L;
        const int m0 = (lane << 2) % 5;
        #pragma unroll
        for (int j = 0; j < 5; ++j) {
            if (256 * j < limp) {
                int4 v4 = ((const int4*)sKp)[lane + 64 * j];
                const int base = 4 * lane + 256 * j;
                int mj = m0 + j; if (mj >= 5) mj -= 5;
                const int v[4] = {v4.x, v4.y, v4.z, v4.w};
                #pragma unroll
                for (int c = 0; c < 4; ++c) {
                    int f = mj + c; if (f >= 5) f -= 5;
                    const bool val = (base + c) < limp;
                    const int vv = v[c];
                    sg += (val && f == 0) ? vv : 0;
                    sk += (val && f == 1) ? vv : 0;
                    sp += (val && f == 2) ? vv : 0;
                    if (val && f >= 3) atomicAdd(&hist[(f == 4 ? 11 : 0) + vv], 1);
                }
            }
        }
        if (hc0) {
            atomicAdd(&hist[45 + qc0.x], 1);
            if (4 * lane + 1 < limc) atomicAdd(&hist[64 + qc0.y], 1);
            if (4 * lane + 2 < limc) atomicAdd(&hist[45 + qc0.z], 1);
            if (4 * lane + 3 < limc) atomicAdd(&hist[64 + qc0.w], 1);
        }
        if (hc1) {
            atomicAdd(&hist[45 + qc1.x], 1);
            if (257 + 4 * lane < limc) atomicAdd(&hist[64 + qc1.y], 1);
            if (258 + 4 * lane < limc) atomicAdd(&hist[45 + qc1.z], 1);
            if (259 + 4 * lane < limc) atomicAdd(&hist[64 + qc1.w], 1);
        }
    }
    #pragma unroll
    for (int d = 32; d; d >>= 1) {
        sg += __shfl_xor(sg, d); sk += __shfl_xor(sk, d); sp += __shfl_xor(sp, d);
    }

    float A;
    {
        float fg = (float)sg, fk = (float)sk, fp = (float)sp;
        A = fmaf(Lf - fg, emb_g[ch], fg * emb_g[32 + ch])
          + fmaf(Lf - fk, emb_k[ch], fk * emb_k[32 + ch])
          + fmaf(Lf - fp, emb_pr[ch], fp * emb_pr[32 + ch]);
        A = h ? 0.f : A;
    }
    {
        const float* tA = h ? emb_pl : emb_j;
        const float* tB = h ? emb_a  : emb_r;
        const int nA = h ? 19 : 11;
        const int nT = h ? 50 : 45;
        const int hb = h ? 45 : 0;
        #pragma unroll 5
        for (int r = 0; r < nT; ++r) {
            const float* p = (r < nA) ? (tA + (r << 5)) : (tB + ((r - nA) << 5));
            A = fmaf((float)hist[hb + r], p[ch], A);
        }
        sPool[(h << 5) + ch] = A * (invL * (h ? 0.5f : 0.2f));
    }
    {
        const float* W2 = h ? w_c2 : w_p2;
        const float* acc = sAcc + (h << 5);
        float v = h ? b_c2[ch] : b_p2[ch];
        #pragma unroll 8
        for (int k = 0; k < 32; ++k)
            v = fmaf(acc[k], W2[(k << 5) + ch], v);
        sPool[64 + (h << 5) + ch] = v;
    }

    {
        float x = b_fc1[lane], y = 0.f;
        #pragma unroll 8
        for (int k = 0; k < 128; k += 2) {
            float w0 = w_fc1[(size_t)k * 64 + lane];
            float w1 = w_fc1[(size_t)(k + 1) * 64 + lane];
            float2 u = *(const float2*)&sPool[k];
            x = fmaf(u.x, w0, x); y = fmaf(u.y, w1, y);
        }
        float hv = fmaxf(x + y, 0.f);
        const float2 wf2 = *(const float2*)&w_fc2[2 * lane];
        float q0 = hv * wf2.x, q1 = hv * wf2.y;
        #pragma unroll
        for (int d = 32; d; d >>= 1) {
            q0 += __shfl_xor(q0, d); q1 += __shfl_xor(q1, d);
        }
        if (lane == 0) {
            float2 o2;
            o2.x = fmaxf(q0 + b_fc2[0], 0.f);
            o2.y = fmaxf(q1 + b_fc2[1], 0.f);
            *(float2*)&out[(size_t)b * 2] = o2;
        }
    }
}

// ---------------- staging (identical in both bodies) ----------------
__device__ __forceinline__ void stage_row(
    const float* __restrict__ cont_p, const float* __restrict__ cont_c,
    const int* __restrict__ cat_p, float* sBuf, int lane, int b, int L)
{
    float* sPc = sBuf;
    float* sCc = sBuf + 768;
    int*   sKp = (int*)(sBuf + 1280);
    const char* gp = (const char*)(cont_p + (size_t)b * 768);
    const char* gc = (const char*)(cont_c + (size_t)b * 512);
    const char* gk = (const char*)(cat_p + (size_t)b * 1280);
    const int lo = 16 * lane;
    const int bP = 12 * L, bC = 8 * L, bK = 20 * L;
    gld16(gp + lo, (char*)sPc);
    if (1024 < bP) gld16(gp + 1024 + lo, (char*)sPc + 1024);
    if (2048 < bP) gld16(gp + 2048 + lo, (char*)sPc + 2048);
    gld16(gc + lo, (char*)sCc);
    if (1024 < bC) gld16(gc + 1024 + lo, (char*)sCc + 1024);
    #pragma unroll
    for (int j = 0; j < 5; ++j)
        if (1024 * j < bK) gld16(gk + 1024 * j + lo, (char*)sKp + 1024 * j);
}

// ---------------- V5 body: token-per-lane, register accumulators ----------------
__device__ __forceinline__ void body_v5(
    const float* __restrict__ cont_p, const float* __restrict__ cont_c,
    const int* __restrict__ cat_p, const int* __restrict__ cat_c,
    const int* __restrict__ lengths,
    const float* __restrict__ w_p1, const float* __restrict__ b_p1,
    const float* __restrict__ w_p2, const float* __restrict__ b_p2,
    const float* __restrict__ w_c1, const float* __restrict__ b_c1,
    const float* __restrict__ w_c2, const float* __restrict__ b_c2,
    const float* __restrict__ emb_g,  const float* __restrict__ emb_k,
    const float* __restrict__ emb_pr, const float* __restrict__ emb_j,
    const float* __restrict__ emb_r,  const float* __restrict__ emb_pl,
    const float* __restrict__ emb_a,
    const float* __restrict__ w_fc1, const float* __restrict__ b_fc1,
    const float* __restrict__ w_fc2, const float* __restrict__ b_fc2,
    float* __restrict__ out, float* sBuf, int lane, int b)
{
    constexpr int S = 256;
    float* sPc  = sBuf;
    float* sCc  = sBuf + 768;
    float* sAcc = sBuf + 768;   // aliases sCc start; written after all reads

    int L = lengths[b]; L = (L < 1) ? 1 : (L > S ? S : L);
    const float Lf = (float)L, invL = 1.0f / Lf;
    const int h = lane >> 5;

    stage_row(cont_p, cont_c, cat_p, sBuf, lane, b, L);

    const int limc = 2 * L;
    const int4* KC = (const int4*)(cat_c + (size_t)b * 512);
    int4 qc0, qc1;
    const bool hc0 = (4 * lane < limc), hc1 = (256 + 4 * lane < limc);
    if (hc0) qc0 = KC[lane];
    if (hc1) qc1 = KC[lane + 64];

    __syncthreads();   // B1: vmcnt drain

    // ---- token phase: lane owns tokens 4*lane..4*lane+3 (distinct reads) ----
    float v[64];
    {
        const float4* tp4 = (const float4*)sPc + 3 * lane;   // 48B/lane
        const float4* tc4 = (const float4*)sCc + 2 * lane;   // 32B/lane
        const float4 a = tp4[0], b4 = tp4[1], c4 = tp4[2];
        const float4 d4 = tc4[0], e4 = tc4[1];
        const int t0 = 4 * lane;
        const bool ok0 = t0 < L, ok1 = t0 + 1 < L, ok2 = t0 + 2 < L, ok3 = t0 + 3 < L;
        #pragma unroll
        for (int ch = 0; ch < 32; ++ch) {
            const float w0 = w_p1[ch], w1 = w_p1[32 + ch], w2 = w_p1[64 + ch];
            const float bb = b_p1[ch];
            float r0 = fmaxf(fmaf(a.x,  w0, fmaf(a.y,  w1, fmaf(a.z,  w2, bb))), 0.f);
            float r1 = fmaxf(fmaf(a.w,  w0, fmaf(b4.x, w1, fmaf(b4.y, w2, bb))), 0.f);
            float r2 = fmaxf(fmaf(b4.z, w0, fmaf(b4.w, w1, fmaf(c4.x, w2, bb))), 0.f);
            float r3 = fmaxf(fmaf(c4.y, w0, fmaf(c4.z, w1, fmaf(c4.w, w2, bb))), 0.f);
            r0 = ok0 ? r0 : 0.f; r1 = ok1 ? r1 : 0.f;   // cndmask: NaN-safe
            r2 = ok2 ? r2 : 0.f; r3 = ok3 ? r3 : 0.f;
            v[ch] = (r0 + r1) + (r2 + r3);
            const float u0 = w_c1[ch], u1 = w_c1[32 + ch], cb = b_c1[ch];
            float s0 = fmaxf(fmaf(d4.x, u0, fmaf(d4.y, u1, cb)), 0.f);
            float s1 = fmaxf(fmaf(d4.z, u0, fmaf(d4.w, u1, cb)), 0.f);
            float s2 = fmaxf(fmaf(e4.x, u0, fmaf(e4.y, u1, cb)), 0.f);
            float s3 = fmaxf(fmaf(e4.z, u0, fmaf(e4.w, u1, cb)), 0.f);
            s0 = ok0 ? s0 : 0.f; s1 = ok1 ? s1 : 0.f;
            s2 = ok2 ? s2 : 0.f; s3 = ok3 ? s3 : 0.f;
            v[32 + ch] = (s0 + s1) + (s2 + s3);
        }
    }
    // ---- butterfly reduce-scatter: lane l ends with sum of v[l] over lanes ----
    #pragma unroll
    for (int c = 0; c < 32; ++c) {
        float send = h ? v[c] : v[c + 32];
        float keep = h ? v[c + 32] : v[c];
        v[c] = keep + __shfl_xor(send, 32);
    }
    {
        const bool s16 = (lane & 16) != 0;
        #pragma unroll
        for (int c = 0; c < 16; ++c) {
            float send = s16 ? v[c] : v[c + 16];
            float keep = s16 ? v[c + 16] : v[c];
            v[c] = keep + __shfl_xor(send, 16);
        }
        const bool s8 = (lane & 8) != 0;
        #pragma unroll
        for (int c = 0; c < 8; ++c) {
            float send = s8 ? v[c] : v[c + 8];
            float keep = s8 ? v[c + 8] : v[c];
            v[c] = keep + __shfl_xor(send, 8);
        }
        const bool s4 = (lane & 4) != 0;
        #pragma unroll
        for (int c = 0; c < 4; ++c) {
            float send = s4 ? v[c] : v[c + 4];
            float keep = s4 ? v[c + 4] : v[c];
            v[c] = keep + __shfl_xor(send, 4);
        }
        const bool s2 = (lane & 2) != 0;
        #pragma unroll
        for (int c = 0; c < 2; ++c) {
            float send = s2 ? v[c] : v[c + 2];
            float keep = s2 ? v[c + 2] : v[c];
            v[c] = keep + __shfl_xor(send, 2);
        }
        const bool s1 = (lane & 1) != 0;
        float send = s1 ? v[0] : v[1];
        float keep = s1 ? v[1] : v[0];
        v[0] = keep + __shfl_xor(send, 1);
    }
    sAcc[lane] = v[0] * invL;   // same layout as R14: (h?aC:aP)[lane&31]
    __syncthreads();   // B2: fence -> hist may overwrite cont_p region

    cat_tail(cat_c, w_p2, b_p2, w_c2, b_c2,
             emb_g, emb_k, emb_pr, emb_j, emb_r, emb_pl, emb_a,
             w_fc1, b_fc1, w_fc2, b_fc2, out,
             sBuf, lane, b, L, Lf, invL, qc0, qc1, hc0, hc1);
}

// ---------------- R14 body (final correctness kernel) ----------------
__device__ __forceinline__ void body_r14(
    const float* __restrict__ cont_p, const float* __restrict__ cont_c,
    const int* __restrict__ cat_p, const int* __restrict__ cat_c,
    const int* __restrict__ lengths,
    const float* __restrict__ w_p1, const float* __restrict__ b_p1,
    const float* __restrict__ w_p2, const float* __restrict__ b_p2,
    const float* __restrict__ w_c1, const float* __restrict__ b_c1,
    const float* __restrict__ w_c2, const float* __restrict__ b_c2,
    const float* __restrict__ emb_g,  const float* __restrict__ emb_k,
    const float* __restrict__ emb_pr, const float* __restrict__ emb_j,
    const float* __restrict__ emb_r,  const float* __restrict__ emb_pl,
    const float* __restrict__ emb_a,
    const float* __restrict__ w_fc1, const float* __restrict__ b_fc1,
    const float* __restrict__ w_fc2, const float* __restrict__ b_fc2,
    float* __restrict__ out, float* sBuf, int lane, int b)
{
    constexpr int S = 256;
    float* sPc  = sBuf;
    float* sCc  = sBuf + 768;
    float* sAcc = sBuf + 768;

    int L = lengths[b]; L = (L < 1) ? 1 : (L > S ? S : L);
    const float Lf = (float)L, invL = 1.0f / Lf;
    const int ch = lane & 31, h = lane >> 5;

    stage_row(cont_p, cont_c, cat_p, sBuf, lane, b, L);

    const int limc = 2 * L;
    const int4* KC = (const int4*)(cat_c + (size_t)b * 512);
    int4 qc0, qc1;
    const bool hc0 = (4 * lane < limc), hc1 = (256 + 4 * lane < limc);
    if (hc0) qc0 = KC[lane];
    if (hc1) qc1 = KC[lane + 64];

    const float wp0 = w_p1[ch], wp1 = w_p1[32 + ch], wp2 = w_p1[64 + ch], bp = b_p1[ch];
    const float wc0 = w_c1[ch], wc1 = w_c1[32 + ch], bc = b_c1[ch];

    __syncthreads();   // B1

    float aP = 0.f, aC = 0.f;
    {
        const int gf = L >> 2;
        const int gh = (gf + 1) >> 1;
        const float4* tp4 = (const float4*)sPc;
        const float4* tc4 = (const float4*)sCc;
        #pragma unroll 4
        for (int i = 0; i < gh; ++i) {
            const int g = h ? gh + i : i;
            if (g < gf) {
                float4 a  = tp4[3 * g], bb = tp4[3 * g + 1], cc = tp4[3 * g + 2];
                float4 d  = tc4[2 * g], ee = tc4[2 * g + 1];
                float p0 = fmaxf(fmaf(a.x,  wp0, fmaf(a.y,  wp1, fmaf(a.z,  wp2, bp))), 0.f);
                float p1 = fmaxf(fmaf(a.w,  wp0, fmaf(bb.x, wp1, fmaf(bb.y, wp2, bp))), 0.f);
                float p2 = fmaxf(fmaf(bb.z, wp0, fmaf(bb.w, wp1, fmaf(cc.x, wp2, bp))), 0.f);
                float p3 = fmaxf(fmaf(cc.y, wp0, fmaf(cc.z, wp1, fmaf(cc.w, wp2, bp))), 0.f);
                aP += (p0 + p1) + (p2 + p3);
                float q0 = fmaxf(fmaf(d.x,  wc0, fmaf(d.y,  wc1, bc)), 0.f);
                float q1 = fmaxf(fmaf(d.z,  wc0, fmaf(d.w,  wc1, bc)), 0.f);
                float q2 = fmaxf(fmaf(ee.x, wc0, fmaf(ee.y, wc1, bc)), 0.f);
                float q3 = fmaxf(fmaf(ee.z, wc0, fmaf(ee.w, wc1, bc)), 0.f);
                aC += (q0 + q1) + (q2 + q3);
            }
        }
        const int rem = L & 3;
        if (h == 0 && rem) {
            const float* tp = sPc + 12 * gf;
            const float* tc = sCc + 8 * gf;
            for (int r = 0; r < rem; ++r) {
                aP += fmaxf(fmaf(tp[3*r], wp0, fmaf(tp[3*r+1], wp1, fmaf(tp[3*r+2], wp2, bp))), 0.f);
                aC += fmaxf(fmaf(tc[2*r], wc0, fmaf(tc[2*r+1], wc1, bc)), 0.f);
            }
        }
        aP += __shfl_xor(aP, 32);
        aC += __shfl_xor(aC, 32);
        sAcc[lane] = (h ? aC : aP) * invL;
    }
    __syncthreads();   // B2

    cat_tail(cat_c, w_p2, b_p2, w_c2, b_c2,
             emb_g, emb_k, emb_pr, emb_j, emb_r, emb_pl, emb_a,
             w_fc1, b_fc1, w_fc2, b_fc2, out,
             sBuf, lane, b, L, Lf, invL, qc0, qc1, hc0, hc1);
}

// ---------------- kernels ----------------
#define ARGS_DECL \
    const float* __restrict__ cont_p, const float* __restrict__ cont_c, \
    const int* __restrict__ cat_p, const int* __restrict__ cat_c, \
    const int* __restrict__ lengths, \
    const float* __restrict__ w_p1, const float* __restrict__ b_p1, \
    const float* __restrict__ w_p2, const float* __restrict__ b_p2, \
    const float* __restrict__ w_c1, const float* __restrict__ b_c1, \
    const float* __restrict__ w_c2, const float* __restrict__ b_c2, \
    const float* __restrict__ emb_g,  const float* __restrict__ emb_k, \
    const float* __restrict__ emb_pr, const float* __restrict__ emb_j, \
    const float* __restrict__ emb_r,  const float* __restrict__ emb_pl, \
    const float* __restrict__ emb_a, \
    const float* __restrict__ w_fc1, const float* __restrict__ b_fc1, \
    const float* __restrict__ w_fc2, const float* __restrict__ b_fc2, \
    float* __restrict__ out

#define ARGS_PASS cont_p, cont_c, cat_p, cat_c, lengths, \
    w_p1, b_p1, w_p2, b_p2, w_c1, b_c1, w_c2, b_c2, \
    emb_g, emb_k, emb_pr, emb_j, emb_r, emb_pl, emb_a, \
    w_fc1, b_fc1, w_fc2, b_fc2, out

__global__ __launch_bounds__(BDIM, 4)
void v5_probe(ARGS_DECL, int rep)
{
    __shared__ __align__(16) float sBuf[2560];
    for (int r = 0; r < rep; ++r) {
        asm volatile("" ::: "memory");
        body_v5(ARGS_PASS, sBuf, (int)threadIdx.x, (int)blockIdx.x);
        __syncthreads();
    }
}

__global__ __launch_bounds__(BDIM)
void mlpreg_kernel(ARGS_DECL)
{
    __shared__ __align__(16) float sBuf[2560];
    body_r14(ARGS_PASS, sBuf, (int)threadIdx.x, (int)blockIdx.x);
}

extern "C" void kernel_launch(void* const* d_in, const int* in_sizes, int n_in,
                              void* d_out, int out_size, void* d_ws, size_t ws_size,
                              hipStream_t stream) {
    const float* cont_p = (const float*)d_in[0];
    const float* cont_c = (const float*)d_in[1];
    const int*   cat_p  = (const int*)d_in[2];
    const int*   cat_c  = (const int*)d_in[3];
    const int*   lens   = (const int*)d_in[4];
    const float* w_p1   = (const float*)d_in[5];
    const float* b_p1   = (const float*)d_in[6];
    const float* w_p2   = (const float*)d_in[7];
    const float* b_p2   = (const float*)d_in[8];
    const float* w_c1   = (const float*)d_in[9];
    const float* b_c1   = (const float*)d_in[10];
    const float* w_c2   = (const float*)d_in[11];
    const float* b_c2   = (const float*)d_in[12];
    const float* emb_g  = (const float*)d_in[13];
    const float* emb_k  = (const float*)d_in[14];
    const float* emb_pr = (const float*)d_in[15];
    const float* emb_j  = (const float*)d_in[16];
    const float* emb_r  = (const float*)d_in[17];
    const float* emb_pl = (const float*)d_in[18];
    const float* emb_a  = (const float*)d_in[19];
    const float* w_fc1  = (const float*)d_in[20];
    const float* b_fc1  = (const float*)d_in[21];
    const float* w_fc2  = (const float*)d_in[22];
    const float* b_fc2  = (const float*)d_in[23];
    float* out = (float*)d_out;

    // V5 probe x REP=8 (visible in top-5 with counters; output overwritten)
    hipLaunchKernelGGL(v5_probe, dim3(4096), dim3(BDIM), 0, stream,
                       cont_p, cont_c, cat_p, cat_c, lens,
                       w_p1, b_p1, w_p2, b_p2, w_c1, b_c1, w_c2, b_c2,
                       emb_g, emb_k, emb_pr, emb_j, emb_r, emb_pl, emb_a,
                       w_fc1, b_fc1, w_fc2, b_fc2, out, 8);
    // final: R14 verbatim (correctness)
    hipLaunchKernelGGL(mlpreg_kernel, dim3(4096), dim3(BDIM), 0, stream,
                       cont_p, cont_c, cat_p, cat_c, lens,
                       w_p1, b_p1, w_p2, b_p2, w_c1, b_c1, w_c2, b_c2,
                       emb_g, emb_k, emb_pr, emb_j, emb_r, emb_pl, emb_a,
                       w_fc1, b_fc1, w_fc2, b_fc2, out);
}